// Round 9
// baseline (315.437 us; speedup 1.0000x reference)
//
#include <hip/hip_runtime.h>
#include <math.h>

#define NN 100000
#define DIN 256
#define DH 128
#define GEMM_NB 1563       // ceil(NN/64)
#define BSHIFT 9
#define BNODES 512                     // nodes per bucket
#define NB_BUCKET 196                  // ceil(NN/512)
#define BCAP 12288                     // bucket capacity (mean 8163, sigma ~90)
#define PA_EDGES 4096                  // edges per pass-A block
#define PREPW_NB 128                   // blocks for W1 pre-swizzle (32768 threads)

using short8  = __attribute__((ext_vector_type(8))) short;
using float4v = __attribute__((ext_vector_type(4))) float;

static __device__ __forceinline__ unsigned short f2bf(float f) {
    unsigned u = __float_as_uint(f);
    unsigned r = u + 0x7fffu + ((u >> 16) & 1u);   // round-to-nearest-even
    return (unsigned short)(r >> 16);
}
static __device__ __forceinline__ float bf_lo(unsigned u) { return __uint_as_float(u << 16); }
static __device__ __forceinline__ float bf_hi(unsigned u) { return __uint_as_float(u & 0xffff0000u); }

// ---------------- K1: pass A (LDS-staged, packed output)  ||  W1 pre-swizzle ----------------
// packed word: (li << 17) | src ; li = d & 511 (bucket implicit by array segment), src < 2^17
__global__ __launch_bounds__(256) void k_partA_prepW(const int* __restrict__ src,
                                                     const int* __restrict__ dst, int E,
                                                     int* __restrict__ bucketFill,
                                                     unsigned* __restrict__ bkArr,
                                                     int pa_nb,
                                                     const float* __restrict__ W1,
                                                     unsigned short* __restrict__ W1p) {
    if ((int)blockIdx.x >= pa_nb) {
        // ---- W1 -> bf16 fragment-order pre-swizzle ----
        int t = ((int)blockIdx.x - pa_nb) * 256 + threadIdx.x;     // 0..32767
        int lane = t & 63;
        int ks   = (t >> 6) & 7;
        int nt   = (t >> 9) & 1;
        int wv   = (t >> 10) & 3;
        int n = wv * 32 + nt * 16 + (lane & 15);
        int kbase = ks * 32 + (lane >> 4) * 8;
        short8 v;
#pragma unroll
        for (int j = 0; j < 8; ++j) v[j] = (short)f2bf(W1[(kbase + j) * DH + n]);
        *(short8*)&W1p[(long long)t * 8] = v;
        return;
    }
    __shared__ int aCnt[NB_BUCKET];
    __shared__ int aBase[NB_BUCKET];
    __shared__ int ds[PA_EDGES];       // 16 KB
    __shared__ int ss[PA_EDGES];       // 16 KB
    const int tid = threadIdx.x;
    for (int i = tid; i < NB_BUCKET; i += 256) aCnt[i] = 0;
    __syncthreads();
    const int e0   = (int)blockIdx.x * PA_EDGES;
    const int eend = min(e0 + PA_EDGES, E);
    const int n    = eend - e0;
    for (int i = tid; i < n; i += 256) {
        int d = dst[e0 + i];
        ds[i] = d;
        ss[i] = src[e0 + i];
        atomicAdd(&aCnt[d >> BSHIFT], 1);
    }
    __syncthreads();
    for (int i = tid; i < NB_BUCKET; i += 256) {
        int c = aCnt[i];
        aBase[i] = c ? atomicAdd(&bucketFill[i], c) : 0;
        aCnt[i] = 0;   // reuse as cursor
    }
    __syncthreads();
    for (int i = tid; i < n; i += 256) {
        int d = ds[i];
        int b = d >> BSHIFT;
        int r = atomicAdd(&aCnt[b], 1);
        bkArr[(long long)b * BCAP + aBase[b] + r] =
            ((unsigned)(d & (BNODES - 1)) << 17) | (unsigned)ss[i];
    }
}

// ---------------- pass B: per-bucket local CSR build (one block per bucket) ----------------
__global__ __launch_bounds__(512) void k_partB(const int* __restrict__ bucketFill,
                                               const unsigned* __restrict__ bkArr,
                                               int* __restrict__ cnt,
                                               int* __restrict__ excl,
                                               float* __restrict__ dinv,
                                               int* __restrict__ eidx) {
    __shared__ int h[BNODES];     // hist, then cursor
    __shared__ int hex[BNODES];   // exclusive prefix within bucket
    __shared__ int st[256];
    const int tid   = threadIdx.x;
    const int b     = blockIdx.x;
    const int nbase = b << BSHIFT;
    const int len   = bucketFill[b];
    const long long abase = (long long)b * BCAP;

    // gbase = sum(bucketFill[0..b-1]) via block reduction
    if (tid < 256) st[tid] = (tid < b) ? bucketFill[tid] : 0;
    __syncthreads();
    for (int off = 128; off > 0; off >>= 1) {
        if (tid < off) st[tid] += st[tid + off];
        __syncthreads();
    }
    const int gbase = st[0];
    __syncthreads();

    for (int i = tid; i < BNODES; i += 512) h[i] = 0;
    __syncthreads();
    for (int k = tid; k < len; k += 512)
        atomicAdd(&h[bkArr[abase + k] >> 17], 1);
    __syncthreads();

    // scan 512 counters: pairwise + Hillis-Steele over 256 pair sums
    int a0 = 0, a1 = 0;
    if (tid < 256) {
        a0 = h[2 * tid]; a1 = h[2 * tid + 1];
        st[tid] = a0 + a1;
    }
    __syncthreads();
    for (int off = 1; off < 256; off <<= 1) {
        int val = (tid < 256 && tid >= off) ? st[tid - off] : 0;
        __syncthreads();
        if (tid < 256) st[tid] += val;
        __syncthreads();
    }
    if (tid < 256) {
        int prev = (tid > 0) ? st[tid - 1] : 0;
        hex[2 * tid]     = prev;
        hex[2 * tid + 1] = prev + a0;
    }
    __syncthreads();

    for (int i = tid; i < BNODES; i += 512) {
        int n = nbase + i;
        if (n < NN) {
            int c = h[i];
            cnt[n]  = c;
            excl[n] = gbase + hex[i];
            dinv[n] = rsqrtf(1.0f + (float)c);
        }
    }
    for (int i = tid; i < BNODES; i += 512) h[i] = 0;   // cursors
    __syncthreads();

    for (int k = tid; k < len; k += 512) {
        unsigned w = bkArr[abase + k];
        int li = (int)(w >> 17);
        int r = atomicAdd(&h[li], 1);
        eidx[gbase + hex[li] + r] = (int)(w & 0x1FFFFu);
    }
}

// ---------------- standalone GEMM (MFMA bf16): hs_bf16 = x @ W1 (UNSCALED) ----------------
__global__ __launch_bounds__(256) void k_gemm(const float* __restrict__ x,
                                              const unsigned short* __restrict__ W1p,
                                              unsigned short* __restrict__ hs) {
    __shared__ unsigned short aL[64 * 32 * 8];   // 32 KB, 16B-chunk XOR swizzle
    const int tid  = threadIdx.x;
    const int wave = tid >> 6;
    const int lane = tid & 63;
    const int quad = lane >> 4;
    const int m16  = lane & 15;
    const int row0 = blockIdx.x * 64;

    short8 bfr[2][8];
#pragma unroll
    for (int nt = 0; nt < 2; ++nt)
#pragma unroll
        for (int ks = 0; ks < 8; ++ks)
            bfr[nt][ks] = ((const short8*)W1p)[((wave * 2 + nt) * 8 + ks) * 64 + lane];

#pragma unroll
    for (int it = 0; it < 8; ++it) {
        int id  = it * 256 + tid;
        int row = id >> 5;
        int kb  = id & 31;
        int gr  = row0 + row;
        float4 f0, f1;
        if (gr < NN) {
            const float* xp = &x[(long long)gr * DIN + kb * 8];
            f0 = *(const float4*)xp;
            f1 = *(const float4*)(xp + 4);
        } else {
            f0 = make_float4(0.f, 0.f, 0.f, 0.f);
            f1 = f0;
        }
        short8 v;
        v[0] = (short)f2bf(f0.x); v[1] = (short)f2bf(f0.y);
        v[2] = (short)f2bf(f0.z); v[3] = (short)f2bf(f0.w);
        v[4] = (short)f2bf(f1.x); v[5] = (short)f2bf(f1.y);
        v[6] = (short)f2bf(f1.z); v[7] = (short)f2bf(f1.w);
        int chunk = row * 32 + (kb ^ (row & 31));
        *(short8*)&aL[chunk * 8] = v;
    }
    __syncthreads();

    float4v acc[4][2];
#pragma unroll
    for (int mt = 0; mt < 4; ++mt)
#pragma unroll
        for (int nt = 0; nt < 2; ++nt)
            acc[mt][nt] = (float4v)(0.0f);

#pragma unroll
    for (int mt = 0; mt < 4; ++mt) {
        int row = mt * 16 + m16;
#pragma unroll
        for (int ks = 0; ks < 8; ++ks) {
            int kb = ks * 4 + quad;
            int chunk = row * 32 + (kb ^ (row & 31));
            short8 a = *(const short8*)&aL[chunk * 8];
            acc[mt][0] = __builtin_amdgcn_mfma_f32_16x16x32_bf16(a, bfr[0][ks], acc[mt][0], 0, 0, 0);
            acc[mt][1] = __builtin_amdgcn_mfma_f32_16x16x32_bf16(a, bfr[1][ks], acc[mt][1], 0, 0, 0);
        }
    }

    const int n0 = wave * 32;
#pragma unroll
    for (int mt = 0; mt < 4; ++mt) {
#pragma unroll
        for (int r = 0; r < 4; ++r) {
            int row = row0 + mt * 16 + quad * 4 + r;
            if (row < NN) {
#pragma unroll
                for (int nt = 0; nt < 2; ++nt)
                    hs[(long long)row * DH + n0 + nt * 16 + m16] = f2bf(acc[mt][nt][r]);
            }
        }
    }
}

// ---------------- fused layer-1 aggregation + layer-2 linear: one wave per node ----------------
__global__ __launch_bounds__(256) void k_agg1l2(const int* __restrict__ eidx,
                                                const int* __restrict__ excl,   // absolute
                                                const int* __restrict__ cnt,
                                                const unsigned* __restrict__ hs2,
                                                const float* __restrict__ dinv,
                                                const float* __restrict__ b1,
                                                const float* __restrict__ W2,
                                                float* __restrict__ zs) {
    int w = (blockIdx.x * 256 + threadIdx.x) >> 6;
    if (w >= NN) return;
    int lane = threadIdx.x & 63;
    int offs = excl[w];
    int c = cnt[w];

    float dw = dinv[w];
    unsigned u = hs2[(long long)w * 64 + lane];   // self-loop
    float ax = dw * bf_lo(u);
    float ay = dw * bf_hi(u);

    int j = 0;
    for (; j + 15 < c; j += 16) {
        int s[16]; float es[16]; unsigned uu[16];
#pragma unroll
        for (int q = 0; q < 16; ++q) s[q] = eidx[offs + j + q];
#pragma unroll
        for (int q = 0; q < 16; ++q) es[q] = dinv[s[q]];
#pragma unroll
        for (int q = 0; q < 16; ++q) uu[q] = hs2[(long long)s[q] * 64 + lane];
#pragma unroll
        for (int q = 0; q < 16; ++q) {
            ax = fmaf(es[q], bf_lo(uu[q]), ax);
            ay = fmaf(es[q], bf_hi(uu[q]), ay);
        }
    }
    if (j + 7 < c) {
        int s[8]; float es[8]; unsigned uu[8];
#pragma unroll
        for (int q = 0; q < 8; ++q) s[q] = eidx[offs + j + q];
#pragma unroll
        for (int q = 0; q < 8; ++q) es[q] = dinv[s[q]];
#pragma unroll
        for (int q = 0; q < 8; ++q) uu[q] = hs2[(long long)s[q] * 64 + lane];
#pragma unroll
        for (int q = 0; q < 8; ++q) {
            ax = fmaf(es[q], bf_lo(uu[q]), ax);
            ay = fmaf(es[q], bf_hi(uu[q]), ay);
        }
        j += 8;
    }
    for (; j + 1 < c; j += 2) {
        int s0 = eidx[offs + j], s1 = eidx[offs + j + 1];
        float e0 = dinv[s0], e1 = dinv[s1];
        unsigned u0 = hs2[(long long)s0 * 64 + lane];
        unsigned u1 = hs2[(long long)s1 * 64 + lane];
        ax = fmaf(e0, bf_lo(u0), ax); ay = fmaf(e0, bf_hi(u0), ay);
        ax = fmaf(e1, bf_lo(u1), ax); ay = fmaf(e1, bf_hi(u1), ay);
    }
    if (j < c) {
        int s0 = eidx[offs + j];
        float e0 = dinv[s0];
        unsigned u0 = hs2[(long long)s0 * 64 + lane];
        ax = fmaf(e0, bf_lo(u0), ax); ay = fmaf(e0, bf_hi(u0), ay);
    }

    float2 bb = ((const float2*)b1)[lane];
    float2 ww = ((const float2*)W2)[lane];
    float r0 = fmaxf(fmaf(dw, ax, bb.x), 0.0f);
    float r1 = fmaxf(fmaf(dw, ay, bb.y), 0.0f);
    float v = r0 * ww.x + r1 * ww.y;
#pragma unroll
    for (int off = 32; off > 0; off >>= 1) v += __shfl_down(v, off);
    if (lane == 0) zs[w] = v * dw;
}

// ---------------- layer-2 aggregation + sigmoid epilogue (ILP-4) ----------------
__global__ void k_agg2_final(const int* __restrict__ eidx,
                             const int* __restrict__ excl,   // absolute
                             const int* __restrict__ cnt,
                             const float* __restrict__ zs,
                             const float* __restrict__ dinv,
                             const float* __restrict__ b2,
                             float* __restrict__ out) {
    int i = blockIdx.x * 256 + threadIdx.x;
    if (i >= NN) return;
    int offs = excl[i];
    int c = cnt[i];
    float v = zs[i];   // self-loop
    int j = 0;
    for (; j + 3 < c; j += 4) {
        int s0 = eidx[offs + j + 0];
        int s1 = eidx[offs + j + 1];
        int s2 = eidx[offs + j + 2];
        int s3 = eidx[offs + j + 3];
        v += zs[s0] + zs[s1] + zs[s2] + zs[s3];
    }
    for (; j < c; ++j) v += zs[eidx[offs + j]];
    float z = fmaf(dinv[i], v, b2[0]);
    out[i] = 1.0f / (1.0f + __expf(-z));
}

extern "C" void kernel_launch(void* const* d_in, const int* in_sizes, int n_in,
                              void* d_out, int out_size, void* d_ws, size_t ws_size,
                              hipStream_t stream) {
    const float* x  = (const float*)d_in[0];
    const int*   ei = (const int*)d_in[1];
    const float* W1 = (const float*)d_in[2];
    const float* b1 = (const float*)d_in[3];
    const float* W2 = (const float*)d_in[4];
    const float* b2 = (const float*)d_in[5];
    float* out = (float*)d_out;

    const int E = in_sizes[1] / 2;
    const int* src = ei;
    const int* dst = ei + E;

    // workspace layout (4-byte units; hs 16B-aligned)
    int* wsi = (int*)d_ws;
    float* dinv       = (float*)wsi;                 // N
    int*   cnt        = wsi + NN;                    // N
    int*   excl       = cnt + NN;                    // N
    float* zs         = (float*)(excl + NN);         // N
    int*   bucketFill = (int*)(zs + NN);             // 256
    unsigned short* W1p = (unsigned short*)(bucketFill + 256);  // 32768 bf16 (= 16384 ints)
    int*   eidx       = (int*)(W1p + 32768);         // E
    unsigned* bkArr   = (unsigned*)(eidx + E);       // NB_BUCKET*BCAP packed words (~9.6 MB)
    unsigned short* hs = (unsigned short*)(bkArr + (long long)NB_BUCKET * BCAP);  // N*128 bf16

    const int nb_nodes = (NN + 255) / 256;
    const int pa_nb = (E + PA_EDGES - 1) / PA_EDGES;

    hipMemsetAsync(bucketFill, 0, NB_BUCKET * sizeof(int), stream);

    k_partA_prepW<<<pa_nb + PREPW_NB, 256, 0, stream>>>(src, dst, E, bucketFill, bkArr,
                                                        pa_nb, W1, W1p);
    k_partB<<<NB_BUCKET, 512, 0, stream>>>(bucketFill, bkArr, cnt, excl, dinv, eidx);
    k_gemm<<<GEMM_NB, 256, 0, stream>>>(x, W1p, hs);

    k_agg1l2<<<(NN * 64 + 255) / 256, 256, 0, stream>>>(eidx, excl, cnt,
                                                        (const unsigned*)hs, dinv, b1, W2, zs);

    k_agg2_final<<<nb_nodes, 256, 0, stream>>>(eidx, excl, cnt, zs, dinv, b2, out);
}